// Round 3
// baseline (363.930 us; speedup 1.0000x reference)
//
#include <hip/hip_runtime.h>
#include <hip/hip_cooperative_groups.h>

namespace cg = cooperative_groups;

#define N_NODES 50000
#define N_EDGES 600000
#define CAP 64                          // bucket slots per node (max deg ~33 for this input)
#define GB1 ((N_NODES + 63) / 64)       // 782 gemm/agg tiles
#define FB  ((N_EDGES + 255) / 256)     // 2344 fill chunks
#define AFB ((N_NODES + 31) / 32)       // 1563 final-agg chunks
#define SL 136

typedef unsigned int u32;
typedef unsigned short u16;
typedef __attribute__((ext_vector_type(8))) short short8;
typedef __attribute__((ext_vector_type(4))) float f32x4;

__device__ __forceinline__ u16 f2bf(float f) {
    u32 u = __float_as_uint(f);
    u32 r = (u + 0x7fffu + ((u >> 16) & 1u)) >> 16;  // RNE
    return (u16)r;
}
__device__ __forceinline__ float bf_lo(u32 u) { return __uint_as_float(u << 16); }
__device__ __forceinline__ float bf_hi(u32 u) { return __uint_as_float(u & 0xffff0000u); }

// One cooperative kernel, 4 phases separated by grid.sync():
//   0: zero deg + transpose W1,W2 to bf16
//   1: gemm1 tiles (MFMA) interleaved with CSR count+fill (atomics hide under MFMA)
//   2: agg1(+bias+ReLU) -> LDS -> gemm2 per 64-node tile
//   3: layer-2 aggregation + head
// Rationale: round-2 showed ~120us of the 168 was inter-dispatch overhead
// (5 dispatches, each individually <44us; work-ideal sum ~50us).

__global__ __launch_bounds__(256) void fused_k(
    const float* __restrict__ x, const int* __restrict__ ei,
    const float* __restrict__ W1, const float* __restrict__ b1,
    const float* __restrict__ W2, const float* __restrict__ b2,
    const float* __restrict__ W3, const float* __restrict__ b3,
    float* __restrict__ out,
    int* __restrict__ deg, int* __restrict__ col,
    u16* __restrict__ W1t, u16* __restrict__ W2t,
    u16* __restrict__ hs1, u16* __restrict__ hs2)
{
    __shared__ u16 As[64 * SL];
    __shared__ u16 Bs[128 * SL];   // gemm1 needs 128 rows; later phases use first 64
    cg::grid_group gg = cg::this_grid();
    const int tid = threadIdx.x;
    const int gsz = gridDim.x;
    const int gtid = blockIdx.x * 256 + tid;
    const int gstride = gsz * 256;

    // ---------------- phase 0: init ----------------
    for (int i = gtid; i < N_NODES / 4; i += gstride)
        ((int4*)deg)[i] = make_int4(0, 0, 0, 0);
    for (int i = gtid; i < 128 * 128; i += gstride) {
        int n = i >> 7, k = i & 127;
        W1t[i] = f2bf(W1[k * 128 + n]);
    }
    for (int i = gtid; i < 64 * 128; i += gstride) {
        int n = i >> 7, k = i & 127;
        W2t[i] = f2bf(W2[k * 64 + n]);
    }
    __threadfence();
    gg.sync();

    // ---------------- phase 1: gemm1 tiles + CSR fill ----------------
    for (int item = blockIdx.x; item < GB1 + FB; item += gsz) {
        if (item >= GB1) {   // CSR count+fill chunk (uniform per block)
            int e = (item - GB1) * 256 + tid;
            if (e < N_EDGES) {
                int s = ei[e];
                int d = ei[N_EDGES + e];
                int r = atomicAdd(&deg[d], 1);
                if (r < CAP) col[((size_t)d << 6) + r] = s;  // guard = corruption insurance
            }
            continue;
        }
        // gemm1 tile: hs1[m0..m0+64) = bf16(x @ W1), N=128, K=128
        const int m0 = item * 64;
        __syncthreads();   // protect LDS reuse across items
        {   // stage A (fp32 -> bf16): thread t handles row t>>2, 32 floats
            int row = tid >> 2, c0 = (tid & 3) * 32;
            bool ok = (m0 + row) < N_NODES;
            const float4* src = (const float4*)&x[(size_t)(m0 + row) * 128 + c0];
            u16* dst = &As[row * SL + c0];
#pragma unroll
            for (int i = 0; i < 8; ++i) {
                float4 v = ok ? src[i] : make_float4(0.f, 0.f, 0.f, 0.f);
                u32 lo = (u32)f2bf(v.x) | ((u32)f2bf(v.y) << 16);
                u32 hi = (u32)f2bf(v.z) | ((u32)f2bf(v.w) << 16);
                *(uint2*)&dst[i * 4] = make_uint2(lo, hi);
            }
        }
        {   // stage B: W1t [128][128]; thread t: row t>>1, 64 u16 = 8 uint4
            int n = tid >> 1, h = (tid & 1) * 64;
            const uint4* src = (const uint4*)&W1t[n * 128 + h];
            u16* dst = &Bs[n * SL + h];
#pragma unroll
            for (int i = 0; i < 8; ++i) *(uint4*)&dst[i * 8] = src[i];
        }
        __syncthreads();
        const int l = tid & 63, w = tid >> 6;
        const int q = l >> 4, r16 = l & 15;
        const int m_off = w * 16;
        f32x4 acc[8] = {};
#pragma unroll
        for (int kt = 0; kt < 128; kt += 32) {
            short8 a = *(const short8*)&As[(m_off + r16) * SL + kt + q * 8];
            short8 bb[8];
#pragma unroll
            for (int tn = 0; tn < 8; ++tn)
                bb[tn] = *(const short8*)&Bs[(tn * 16 + r16) * SL + kt + q * 8];
#pragma unroll
            for (int tn = 0; tn < 8; ++tn)
                acc[tn] = __builtin_amdgcn_mfma_f32_16x16x32_bf16(a, bb[tn], acc[tn], 0, 0, 0);
        }
#pragma unroll
        for (int r = 0; r < 4; ++r) {
            int row = m0 + m_off + q * 4 + r;
            if (row < N_NODES) {
#pragma unroll
                for (int tn = 0; tn < 8; ++tn)
                    hs1[(size_t)row * 128 + tn * 16 + r16] = f2bf(acc[tn][r]);
            }
        }
    }
    __threadfence();
    gg.sync();

    // ---------------- phase 2: agg1(+b1+ReLU) -> gemm2 -> hs2 ----------------
    for (int item = blockIdx.x; item < GB1; item += gsz) {
        const int m0 = item * 64;
        __syncthreads();   // protect LDS reuse across items
        {   // stage Bs: W2t [64][128]
            int n = tid >> 2, s0 = (tid & 3) * 32;
            const uint4* src = (const uint4*)&W2t[n * 128 + s0];
            u16* dst = &Bs[n * SL + s0];
#pragma unroll
            for (int i = 0; i < 4; ++i) *(uint4*)&dst[i * 8] = src[i];
        }
        const uint4* rows = (const uint4*)hs1;  // 16 uint4 per 128-feat row
        const int lane = tid & 15;
        const int sub = lane & 7;
        const int fo = lane * 8;
#pragma unroll
        for (int p = 0; p < 4; ++p) {
            int nl = p * 16 + (tid >> 4);      // node_local in [0,64)
            int node = m0 + nl;
            uint4 pk = make_uint4(0, 0, 0, 0);
            if (node < N_NODES) {
                int dg = deg[node];
                float dv = rsqrtf((float)(dg + 1));
                float acc[8];
                uint4 sv = rows[(size_t)node * 16 + lane];  // self-loop
                acc[0] = dv * bf_lo(sv.x); acc[1] = dv * bf_hi(sv.x);
                acc[2] = dv * bf_lo(sv.y); acc[3] = dv * bf_hi(sv.y);
                acc[4] = dv * bf_lo(sv.z); acc[5] = dv * bf_hi(sv.z);
                acc[6] = dv * bf_lo(sv.w); acc[7] = dv * bf_hi(sv.w);
                const int* crow = col + ((size_t)node << 6);
                int c = crow[sub];
                c = (sub < dg) ? c : 0;
                float scr = rsqrtf((float)(deg[c] + 1));
                float sc = (sub < dg) ? scr : 0.f;
                for (int r0 = 0; r0 < dg; r0 += 8) {
                    int jn = r0 + 8 + sub;   // prefetch next round
                    int cn = crow[jn & (CAP - 1)];
                    cn = (jn < dg) ? cn : 0;
                    float scnr = rsqrtf((float)(deg[cn] + 1));
                    float scn = (jn < dg) ? scnr : 0.f;
#pragma unroll
                    for (int jj = 0; jj < 8; ++jj) {
                        int cj = __shfl(c, jj, 16);
                        float scj = __shfl(sc, jj, 16);   // 0 for padding slots
                        uint4 v = rows[(size_t)cj * 16 + lane];
                        acc[0] = fmaf(scj, bf_lo(v.x), acc[0]);
                        acc[1] = fmaf(scj, bf_hi(v.x), acc[1]);
                        acc[2] = fmaf(scj, bf_lo(v.y), acc[2]);
                        acc[3] = fmaf(scj, bf_hi(v.y), acc[3]);
                        acc[4] = fmaf(scj, bf_lo(v.z), acc[4]);
                        acc[5] = fmaf(scj, bf_hi(v.z), acc[5]);
                        acc[6] = fmaf(scj, bf_lo(v.w), acc[6]);
                        acc[7] = fmaf(scj, bf_hi(v.w), acc[7]);
                    }
                    c = cn; sc = scn;
                }
                u32 w0[4];
#pragma unroll
                for (int jq = 0; jq < 4; ++jq) {
                    u16 a = f2bf(fmaxf(fmaf(dv, acc[2 * jq], b1[fo + 2 * jq]), 0.f));
                    u16 bq = f2bf(fmaxf(fmaf(dv, acc[2 * jq + 1], b1[fo + 2 * jq + 1]), 0.f));
                    w0[jq] = (u32)a | ((u32)bq << 16);
                }
                pk = make_uint4(w0[0], w0[1], w0[2], w0[3]);
            }
            *(uint4*)&As[nl * SL + fo] = pk;
        }
        __syncthreads();
        // gemm2: M=64, N=64, K=128; output scaled by dinv[row] (layer-2 src scale)
        const int l = tid & 63, w = tid >> 6;
        const int q = l >> 4, r16 = l & 15;
        const int m_off = w * 16;
        f32x4 acc2[4] = {};
#pragma unroll
        for (int kt = 0; kt < 128; kt += 32) {
            short8 a = *(const short8*)&As[(m_off + r16) * SL + kt + q * 8];
            short8 bb[4];
#pragma unroll
            for (int tn = 0; tn < 4; ++tn)
                bb[tn] = *(const short8*)&Bs[(tn * 16 + r16) * SL + kt + q * 8];
#pragma unroll
            for (int tn = 0; tn < 4; ++tn)
                acc2[tn] = __builtin_amdgcn_mfma_f32_16x16x32_bf16(a, bb[tn], acc2[tn], 0, 0, 0);
        }
#pragma unroll
        for (int r = 0; r < 4; ++r) {
            int row = m0 + m_off + q * 4 + r;
            if (row < N_NODES) {
                float dvr = rsqrtf((float)(deg[row] + 1));
#pragma unroll
                for (int tn = 0; tn < 4; ++tn)
                    hs2[(size_t)row * 64 + tn * 16 + r16] = f2bf(acc2[tn][r] * dvr);
            }
        }
    }
    __threadfence();
    gg.sync();

    // ---------------- phase 3: layer-2 aggregation + head ----------------
    for (int item = blockIdx.x; item < AFB; item += gsz) {
        int node = item * 32 + (tid >> 3);
        int lane = tid & 7;
        if (node < N_NODES) {
            const uint4* rows = (const uint4*)hs2;  // 8 uint4 per 64-feat row
            int dg = deg[node];
            float acc[8] = {};
            auto accum = [&](uint4 v) {
                acc[0] += bf_lo(v.x); acc[1] += bf_hi(v.x);
                acc[2] += bf_lo(v.y); acc[3] += bf_hi(v.y);
                acc[4] += bf_lo(v.z); acc[5] += bf_hi(v.z);
                acc[6] += bf_lo(v.w); acc[7] += bf_hi(v.w);
            };
            accum(rows[(size_t)node * 8 + lane]);  // self-loop (carries dinv[node])
            const int* crow = col + ((size_t)node << 6);
            int c = crow[lane];
            c = (lane < dg) ? c : 0;
            for (int r0 = 0; r0 < dg; r0 += 8) {
                int jn = r0 + 8 + lane;
                int cn = crow[jn & (CAP - 1)];
                cn = (jn < dg) ? cn : 0;
#pragma unroll
                for (int jj = 0; jj < 8; ++jj) {
                    int cj = __shfl(c, jj, 8);
                    uint4 v = rows[(size_t)cj * 8 + lane];
                    uint4 vv = (r0 + jj < dg) ? v : make_uint4(0, 0, 0, 0);
                    accum(vv);
                }
                c = cn;
            }
            float dv = rsqrtf((float)(dg + 1));
            int fo = lane * 8;
            float vsum = 0.f;
#pragma unroll
            for (int jq = 0; jq < 8; ++jq)
                vsum += fmaxf(fmaf(dv, acc[jq], b2[fo + jq]), 0.f) * W3[fo + jq];
#pragma unroll
            for (int m = 4; m > 0; m >>= 1) vsum += __shfl_xor(vsum, m, 64);
            if (lane == 0) out[node] = vsum + b3[0];
        }
    }
}

// ---------------- launch ----------------

extern "C" void kernel_launch(void* const* d_in, const int* in_sizes, int n_in,
                              void* d_out, int out_size, void* d_ws, size_t ws_size,
                              hipStream_t stream) {
    const float* x  = (const float*)d_in[0];
    const int*   ei = (const int*)d_in[1];
    const float* W1 = (const float*)d_in[2];
    const float* b1 = (const float*)d_in[3];
    const float* W2 = (const float*)d_in[4];
    const float* b2 = (const float*)d_in[5];
    const float* W3 = (const float*)d_in[6];
    const float* b3 = (const float*)d_in[7];
    float* out = (float*)d_out;

    char* ws = (char*)d_ws;
    size_t off = 0;
    auto alloc = [&](size_t bytes) -> void* {
        void* p = ws + off;
        off = (off + bytes + 255) & ~(size_t)255;
        return p;
    };
    int* deg = (int*)alloc(N_NODES * sizeof(int));
    int* col = (int*)alloc(((size_t)N_NODES * CAP + 64) * sizeof(int));  // +pad for prefetch
    u16* W1t = (u16*)alloc(128 * 128 * sizeof(u16));
    u16* W2t = (u16*)alloc(64 * 128 * sizeof(u16));
    u16* hs1 = (u16*)alloc((size_t)N_NODES * 128 * sizeof(u16));
    u16* hs2 = (u16*)alloc((size_t)N_NODES * 64 * sizeof(u16));

    // grid sized for guaranteed co-residency (cooperative launch requirement)
    static int nblk = -1;
    if (nblk < 0) {
        int bpc = 0;
        if (hipOccupancyMaxActiveBlocksPerMultiprocessor(&bpc, fused_k, 256, 0) != hipSuccess
            || bpc <= 0)
            bpc = 1;   // conservative fallback: 1 block/CU is always co-resident
        int ncu = 0;
        if (hipDeviceGetAttribute(&ncu, hipDeviceAttributeMultiprocessorCount, 0) != hipSuccess
            || ncu <= 0)
            ncu = 256;
        nblk = bpc * ncu;
    }

    void* args[] = {(void*)&x, (void*)&ei, (void*)&W1, (void*)&b1, (void*)&W2, (void*)&b2,
                    (void*)&W3, (void*)&b3, (void*)&out, (void*)&deg, (void*)&col,
                    (void*)&W1t, (void*)&W2t, (void*)&hs1, (void*)&hs2};
    hipLaunchCooperativeKernel((const void*)fused_k, dim3(nblk), dim3(256), args, 0, stream);
}

// Round 4
// 173.364 us; speedup vs baseline: 2.0992x; 2.0992x over previous
//
#include <hip/hip_runtime.h>

#define N_NODES 50000
#define N_EDGES 600000
#define CAP 64                          // bucket slots per node (max deg ~33 for this input)
#define GB1 ((N_NODES + 63) / 64)       // gemm1 / agg tiles
#define FB  ((N_EDGES + 255) / 256)     // count+fill blocks

typedef unsigned int u32;
typedef unsigned short u16;
typedef __attribute__((ext_vector_type(8))) short short8;
typedef __attribute__((ext_vector_type(4))) float f32x4;

__device__ __forceinline__ u16 f2bf(float f) {
    u32 u = __float_as_uint(f);
    u32 r = (u + 0x7fffu + ((u >> 16) & 1u)) >> 16;  // RNE
    return (u16)r;
}
__device__ __forceinline__ float bf_lo(u32 u) { return __uint_as_float(u << 16); }
__device__ __forceinline__ float bf_hi(u32 u) { return __uint_as_float(u & 0xffff0000u); }

// ---------------- D1: atomic count+fill (bucket CSR) + weight transpose ----
// NO LDS here: atomics need max waves/CU to hide latency (round-1/3 lesson:
// running these at 3 blocks/CU inside an LDS-heavy kernel costs 66us).

__global__ __launch_bounds__(256) void fill_transpose(const int* __restrict__ ei,
                                                      int* __restrict__ deg,
                                                      int* __restrict__ col,
                                                      const float* __restrict__ W1,
                                                      const float* __restrict__ W2,
                                                      u16* __restrict__ W1t,
                                                      u16* __restrict__ W2t) {
    int b = blockIdx.x, t = threadIdx.x;
    if (b < FB) {
        int e = b * 256 + t;
        if (e < N_EDGES) {
            int s = ei[e];
            int d = ei[N_EDGES + e];
            int r = atomicAdd(&deg[d], 1);
            if (r < CAP) col[((size_t)d << 6) + r] = s;   // guard = corruption insurance
        }
    } else if (b < FB + 64) {
        int i = (b - FB) * 256 + t;          // [0, 128*128)
        int n = i >> 7, k = i & 127;
        W1t[i] = f2bf(W1[k * 128 + n]);
    } else {
        int j = (b - FB - 64) * 256 + t;     // [0, 64*128)
        int n = j >> 7, k = j & 127;
        W2t[j] = f2bf(W2[k * 64 + n]);
    }
}

// ---------------- D2: gemm1 (unscaled): hs1 = bf16(x @ W1) ----------------

#define SL 136

__global__ __launch_bounds__(256) void gemm1_k(const float* __restrict__ A,
                                               const u16* __restrict__ Bt,
                                               u16* __restrict__ out) {
    __shared__ u16 As[64 * SL];
    __shared__ u16 Bs[128 * SL];
    const int tid = threadIdx.x;
    const int m0 = blockIdx.x * 64;
    {   // stage A (fp32 -> bf16): thread t handles row t>>2, 32 floats
        int row = tid >> 2, c0 = (tid & 3) * 32;
        bool ok = (m0 + row) < N_NODES;
        const float4* src = (const float4*)&A[(size_t)(m0 + row) * 128 + c0];
        u16* dst = &As[row * SL + c0];
#pragma unroll
        for (int i = 0; i < 8; ++i) {
            float4 v = ok ? src[i] : make_float4(0.f, 0.f, 0.f, 0.f);
            u32 lo = (u32)f2bf(v.x) | ((u32)f2bf(v.y) << 16);
            u32 hi = (u32)f2bf(v.z) | ((u32)f2bf(v.w) << 16);
            *(uint2*)&dst[i * 4] = make_uint2(lo, hi);
        }
    }
    {   // stage B: W1t [128][128]; thread t: row t>>1, 64 u16 = 8 uint4
        int n = tid >> 1, h = (tid & 1) * 64;
        const uint4* src = (const uint4*)&Bt[n * 128 + h];
        u16* dst = &Bs[n * SL + h];
#pragma unroll
        for (int i = 0; i < 8; ++i) *(uint4*)&dst[i * 8] = src[i];
    }
    __syncthreads();

    const int l = tid & 63, w = tid >> 6;
    const int q = l >> 4, r16 = l & 15;
    const int m_off = w * 16;
    f32x4 acc[8] = {};
#pragma unroll
    for (int kt = 0; kt < 128; kt += 32) {
        short8 a = *(const short8*)&As[(m_off + r16) * SL + kt + q * 8];
        short8 bb[8];
#pragma unroll
        for (int tn = 0; tn < 8; ++tn)
            bb[tn] = *(const short8*)&Bs[(tn * 16 + r16) * SL + kt + q * 8];
#pragma unroll
        for (int tn = 0; tn < 8; ++tn)
            acc[tn] = __builtin_amdgcn_mfma_f32_16x16x32_bf16(a, bb[tn], acc[tn], 0, 0, 0);
    }
#pragma unroll
    for (int r = 0; r < 4; ++r) {
        int row = m0 + m_off + q * 4 + r;
        if (row < N_NODES) {
#pragma unroll
            for (int tn = 0; tn < 8; ++tn)
                out[(size_t)row * 128 + tn * 16 + r16] = f2bf(acc[tn][r]);
        }
    }
}

// ---------------- D3: agg1(+bias+ReLU) -> LDS -> gemm2 --------------------
// MLP restructure: all 4 passes' node meta / round-0 cols / deg[col] scale
// chains issued up front (4 parallel chains, not 4 serial); 16-wide rounds
// (1 round covers deg<=16, ~90% of nodes); within a round two 8-gather
// batches whose addresses depend only on shuffles.

__global__ __launch_bounds__(256) void agg_gemm2(const u16* __restrict__ hs,
                                                 const int* __restrict__ deg,
                                                 const int* __restrict__ col,
                                                 const float* __restrict__ bias,
                                                 const u16* __restrict__ Bt,
                                                 u16* __restrict__ out) {
    __shared__ u16 As[64 * SL];
    __shared__ u16 Bs[64 * SL];
    const int tid = threadIdx.x;
    const int m0 = blockIdx.x * 64;
    {   // stage Bs: W2t [64][128]; thread t: row t>>2, 32 u16 = 4 uint4
        int n = tid >> 2, s0 = (tid & 3) * 32;
        const uint4* src = (const uint4*)&Bt[n * 128 + s0];
        u16* dst = &Bs[n * SL + s0];
#pragma unroll
        for (int i = 0; i < 4; ++i) *(uint4*)&dst[i * 8] = src[i];
    }
    const uint4* rows = (const uint4*)hs;  // 16 uint4 per 128-feat row
    const int lane = tid & 15;             // feature lane (16B chunk)
    const int grp = tid >> 4;              // 16 node-groups
    const int fo = lane * 8;

    // ---- prologue: resolve all 4 passes up front ----
    int nd[4], dgv[4], c1[4], d1[4];
    uint4 sv[4];
    float bv[8];
#pragma unroll
    for (int p = 0; p < 4; ++p) {
        int node = m0 + p * 16 + grp;
        nd[p] = node < N_NODES ? node : 0;   // clamp; invalid rows masked at store
    }
#pragma unroll
    for (int p = 0; p < 4; ++p) dgv[p] = deg[nd[p]];
#pragma unroll
    for (int p = 0; p < 4; ++p) sv[p] = rows[(size_t)nd[p] * 16 + lane];
#pragma unroll
    for (int p = 0; p < 4; ++p) c1[p] = col[((size_t)nd[p] << 6) + lane];
#pragma unroll
    for (int j = 0; j < 8; ++j) bv[j] = bias[fo + j];
#pragma unroll
    for (int p = 0; p < 4; ++p) c1[p] = (lane < dgv[p]) ? c1[p] : 0;
#pragma unroll
    for (int p = 0; p < 4; ++p) d1[p] = deg[c1[p]];
    float s1[4];
#pragma unroll
    for (int p = 0; p < 4; ++p)
        s1[p] = (lane < dgv[p]) ? rsqrtf((float)(d1[p] + 1)) : 0.f;

#pragma unroll
    for (int p = 0; p < 4; ++p) {
        const int dg = dgv[p];
        const float dv = rsqrtf((float)(dg + 1));
        float acc[8];
        acc[0] = dv * bf_lo(sv[p].x); acc[1] = dv * bf_hi(sv[p].x);
        acc[2] = dv * bf_lo(sv[p].y); acc[3] = dv * bf_hi(sv[p].y);
        acc[4] = dv * bf_lo(sv[p].z); acc[5] = dv * bf_hi(sv[p].z);
        acc[6] = dv * bf_lo(sv[p].w); acc[7] = dv * bf_hi(sv[p].w);

        auto do8 = [&](int creg, float sreg, int h) {
            int cj[8]; float sj[8]; uint4 v[8];
#pragma unroll
            for (int j = 0; j < 8; ++j) {
                cj[j] = __shfl(creg, h * 8 + j, 16);
                sj[j] = __shfl(sreg, h * 8 + j, 16);
            }
#pragma unroll
            for (int j = 0; j < 8; ++j) v[j] = rows[(size_t)cj[j] * 16 + lane];
#pragma unroll
            for (int j = 0; j < 8; ++j) {
                acc[0] = fmaf(sj[j], bf_lo(v[j].x), acc[0]);
                acc[1] = fmaf(sj[j], bf_hi(v[j].x), acc[1]);
                acc[2] = fmaf(sj[j], bf_lo(v[j].y), acc[2]);
                acc[3] = fmaf(sj[j], bf_hi(v[j].y), acc[3]);
                acc[4] = fmaf(sj[j], bf_lo(v[j].z), acc[4]);
                acc[5] = fmaf(sj[j], bf_hi(v[j].z), acc[5]);
                acc[6] = fmaf(sj[j], bf_lo(v[j].w), acc[6]);
                acc[7] = fmaf(sj[j], bf_hi(v[j].w), acc[7]);
            }
        };

        int cc = c1[p];
        float ss = s1[p];
        int base = 0;
        while (true) {                       // slots [base, base+16)
            do8(cc, ss, 0);
            if (base + 8 < dg) do8(cc, ss, 1);
            base += 16;
            if (base >= dg) break;           // uniform per 16-lane group
            int slot = base + lane;          // rare: deg > 16
            int cn = col[((size_t)nd[p] << 6) + (slot & (CAP - 1))];
            cn = (slot < dg) ? cn : 0;
            cc = cn;
            ss = (slot < dg) ? rsqrtf((float)(deg[cn] + 1)) : 0.f;
        }

        u32 w0[4];
#pragma unroll
        for (int jq = 0; jq < 4; ++jq) {
            u16 a = f2bf(fmaxf(fmaf(dv, acc[2 * jq], bv[2 * jq]), 0.f));
            u16 b = f2bf(fmaxf(fmaf(dv, acc[2 * jq + 1], bv[2 * jq + 1]), 0.f));
            w0[jq] = (u32)a | ((u32)b << 16);
        }
        *(uint4*)&As[(p * 16 + grp) * SL + fo] = make_uint4(w0[0], w0[1], w0[2], w0[3]);
    }
    __syncthreads();

    // gemm2 phase: M=64, N=64, K=128; output pre-scaled by dinv[row]
    const int l = tid & 63, w = tid >> 6;
    const int q = l >> 4, r16 = l & 15;
    const int m_off = w * 16;
    f32x4 acc2[4] = {};
#pragma unroll
    for (int kt = 0; kt < 128; kt += 32) {
        short8 a = *(const short8*)&As[(m_off + r16) * SL + kt + q * 8];
        short8 bb[4];
#pragma unroll
        for (int tn = 0; tn < 4; ++tn)
            bb[tn] = *(const short8*)&Bs[(tn * 16 + r16) * SL + kt + q * 8];
#pragma unroll
        for (int tn = 0; tn < 4; ++tn)
            acc2[tn] = __builtin_amdgcn_mfma_f32_16x16x32_bf16(a, bb[tn], acc2[tn], 0, 0, 0);
    }
#pragma unroll
    for (int r = 0; r < 4; ++r) {
        int row = m0 + m_off + q * 4 + r;
        if (row < N_NODES) {
            float dvr = rsqrtf((float)(deg[row] + 1));
#pragma unroll
            for (int tn = 0; tn < 4; ++tn)
                out[(size_t)row * 64 + tn * 16 + r16] = f2bf(acc2[tn][r] * dvr);
        }
    }
}

// ---------------- D4: layer-2 aggregation + head --------------------------
// hs2 rows already carry dinv[src] -> no deg[col] chain at all. All cols for
// slots 0..31 resolved up front (covers max deg ~33 minus rare tail).

__global__ __launch_bounds__(256) void agg_final_bf(const u16* __restrict__ hs,
                                                    const int* __restrict__ deg,
                                                    const int* __restrict__ col,
                                                    const float* __restrict__ b2,
                                                    const float* __restrict__ W3,
                                                    const float* __restrict__ b3,
                                                    float* __restrict__ out) {
    int node = blockIdx.x * 32 + (threadIdx.x >> 3);
    int lane = threadIdx.x & 7;
    if (node >= N_NODES) return;
    const uint4* rows = (const uint4*)hs;  // 8 uint4 per 64-feat row
    const int* crow = col + ((size_t)node << 6);
    int dg = deg[node];
    // resolve slots 0..31 + self row up front (independent loads)
    int ca = crow[lane];
    int cb = crow[8 + lane];
    int cc = crow[16 + lane];
    int cd = crow[24 + lane];
    uint4 selfv = rows[(size_t)node * 8 + lane];
    ca = (lane < dg) ? ca : 0;
    cb = (8 + lane < dg) ? cb : 0;
    cc = (16 + lane < dg) ? cc : 0;
    cd = (24 + lane < dg) ? cd : 0;

    float acc[8];
    acc[0] = bf_lo(selfv.x); acc[1] = bf_hi(selfv.x);
    acc[2] = bf_lo(selfv.y); acc[3] = bf_hi(selfv.y);
    acc[4] = bf_lo(selfv.z); acc[5] = bf_hi(selfv.z);
    acc[6] = bf_lo(selfv.w); acc[7] = bf_hi(selfv.w);

    auto batch8 = [&](int creg, int base) {
        int cj[8]; uint4 v[8];
#pragma unroll
        for (int j = 0; j < 8; ++j) cj[j] = __shfl(creg, j, 8);
#pragma unroll
        for (int j = 0; j < 8; ++j) v[j] = rows[(size_t)cj[j] * 8 + lane];
#pragma unroll
        for (int j = 0; j < 8; ++j) {
            uint4 vv = (base + j < dg) ? v[j] : make_uint4(0, 0, 0, 0);
            acc[0] += bf_lo(vv.x); acc[1] += bf_hi(vv.x);
            acc[2] += bf_lo(vv.y); acc[3] += bf_hi(vv.y);
            acc[4] += bf_lo(vv.z); acc[5] += bf_hi(vv.z);
            acc[6] += bf_lo(vv.w); acc[7] += bf_hi(vv.w);
        }
    };
    batch8(ca, 0);
    if (dg > 8)  batch8(cb, 8);
    if (dg > 16) batch8(cc, 16);
    if (dg > 24) batch8(cd, 24);
    for (int base = 32; base < dg; base += 8) {   // ultra-rare (deg > 32)
        int ce = crow[(base + lane) & (CAP - 1)];
        ce = (base + lane < dg) ? ce : 0;
        batch8(ce, base);
    }

    float dv = rsqrtf((float)(dg + 1));
    int fo = lane * 8;
    float vsum = 0.f;
#pragma unroll
    for (int jq = 0; jq < 8; ++jq)
        vsum += fmaxf(fmaf(dv, acc[jq], b2[fo + jq]), 0.f) * W3[fo + jq];
#pragma unroll
    for (int m = 4; m > 0; m >>= 1) vsum += __shfl_xor(vsum, m, 64);
    if (lane == 0) out[node] = vsum + b3[0];
}

// ---------------- launch ----------------

extern "C" void kernel_launch(void* const* d_in, const int* in_sizes, int n_in,
                              void* d_out, int out_size, void* d_ws, size_t ws_size,
                              hipStream_t stream) {
    const float* x  = (const float*)d_in[0];
    const int*   ei = (const int*)d_in[1];
    const float* W1 = (const float*)d_in[2];
    const float* b1 = (const float*)d_in[3];
    const float* W2 = (const float*)d_in[4];
    const float* b2 = (const float*)d_in[5];
    const float* W3 = (const float*)d_in[6];
    const float* b3 = (const float*)d_in[7];
    float* out = (float*)d_out;

    char* ws = (char*)d_ws;
    size_t off = 0;
    auto alloc = [&](size_t bytes) -> void* {
        void* p = ws + off;
        off = (off + bytes + 255) & ~(size_t)255;
        return p;
    };
    int* deg = (int*)alloc(N_NODES * sizeof(int));
    int* col = (int*)alloc(((size_t)N_NODES * CAP + 64) * sizeof(int));  // +pad
    u16* W1t = (u16*)alloc(128 * 128 * sizeof(u16));
    u16* W2t = (u16*)alloc(64 * 128 * sizeof(u16));
    u16* hs1 = (u16*)alloc((size_t)N_NODES * 128 * sizeof(u16));
    u16* hs2 = (u16*)alloc((size_t)N_NODES * 64 * sizeof(u16));

    hipMemsetAsync(deg, 0, N_NODES * sizeof(int), stream);
    fill_transpose<<<FB + 96, 256, 0, stream>>>(ei, deg, col, W1, W2, W1t, W2t);
    gemm1_k<<<GB1, 256, 0, stream>>>(x, W1t, hs1);
    agg_gemm2<<<(N_NODES + 63) / 64, 256, 0, stream>>>(hs1, deg, col, b1, W2t, hs2);
    agg_final_bf<<<(N_NODES + 31) / 32, 256, 0, stream>>>(hs2, deg, col, b2, W3, b3, out);
}

// Round 5
// 173.316 us; speedup vs baseline: 2.0998x; 1.0003x over previous
//
#include <hip/hip_runtime.h>

#define N_NODES 50000
#define N_EDGES 600000
#define CAP 64                          // bucket slots per node (max deg ~33 for this input)
#define GB1 ((N_NODES + 63) / 64)       // gemm1 / agg tiles
#define FB  ((N_EDGES + 255) / 256)     // fill blocks
#define SL 136

typedef unsigned int u32;
typedef unsigned short u16;
typedef __attribute__((ext_vector_type(8))) short short8;
typedef __attribute__((ext_vector_type(4))) float f32x4;

__device__ __forceinline__ u16 f2bf(float f) {
    u32 u = __float_as_uint(f);
    u32 r = (u + 0x7fffu + ((u >> 16) & 1u)) >> 16;  // RNE
    return (u16)r;
}
__device__ __forceinline__ float bf_lo(u32 u) { return __uint_as_float(u << 16); }
__device__ __forceinline__ float bf_hi(u32 u) { return __uint_as_float(u & 0xffff0000u); }

// ---------------- D1: gemm1 + deg-zero (replaces memset + transpose disp) --
// hs1 = bf16(x @ W1), unscaled (per-edge norm applied in agg).
// W1 is transposed fp32->bf16 straight into LDS (no global W1t round-trip).
// deg zeroing rides along: nothing in this dispatch reads deg, and the next
// dispatch (fill) sees it complete via stream order.

__global__ __launch_bounds__(256) void gemm1z_k(const float* __restrict__ A,
                                                const float* __restrict__ W1,
                                                u16* __restrict__ out,
                                                int* __restrict__ deg) {
    __shared__ u16 As[64 * SL];
    __shared__ u16 Bs[128 * SL];
    const int tid = threadIdx.x;
    const int m0 = blockIdx.x * 64;
    {   // deg zero: 12500 int4 over 782 blocks (only first 49 blocks active)
        int di = blockIdx.x * 256 + tid;
        if (di < N_NODES / 4) ((int4*)deg)[di] = make_int4(0, 0, 0, 0);
    }
    {   // stage A (fp32 -> bf16): thread t handles row t>>2, 32 floats
        int row = tid >> 2, c0 = (tid & 3) * 32;
        bool ok = (m0 + row) < N_NODES;
        const float4* src = (const float4*)&A[(size_t)(m0 + row) * 128 + c0];
        u16* dst = &As[row * SL + c0];
#pragma unroll
        for (int i = 0; i < 8; ++i) {
            float4 v = ok ? src[i] : make_float4(0.f, 0.f, 0.f, 0.f);
            u32 lo = (u32)f2bf(v.x) | ((u32)f2bf(v.y) << 16);
            u32 hi = (u32)f2bf(v.z) | ((u32)f2bf(v.w) << 16);
            *(uint2*)&dst[i * 4] = make_uint2(lo, hi);
        }
    }
    {   // stage B: Bs[n][k] = bf16(W1[k][n]); W1 fp32 [128][128] row-major.
        // thread: n0=(t&31)*4 (4 cols), kp=t>>5 (k-pair), 8 passes over k.
        int n0 = (tid & 31) * 4, kp = tid >> 5;
#pragma unroll
        for (int p = 0; p < 8; ++p) {
            int k = p * 16 + kp * 2;
            float4 r0 = *(const float4*)&W1[(k) * 128 + n0];
            float4 r1 = *(const float4*)&W1[(k + 1) * 128 + n0];
            *(u32*)&Bs[(n0 + 0) * SL + k] = (u32)f2bf(r0.x) | ((u32)f2bf(r1.x) << 16);
            *(u32*)&Bs[(n0 + 1) * SL + k] = (u32)f2bf(r0.y) | ((u32)f2bf(r1.y) << 16);
            *(u32*)&Bs[(n0 + 2) * SL + k] = (u32)f2bf(r0.z) | ((u32)f2bf(r1.z) << 16);
            *(u32*)&Bs[(n0 + 3) * SL + k] = (u32)f2bf(r0.w) | ((u32)f2bf(r1.w) << 16);
        }
    }
    __syncthreads();

    const int l = tid & 63, w = tid >> 6;
    const int q = l >> 4, r16 = l & 15;
    const int m_off = w * 16;
    f32x4 acc[8] = {};
#pragma unroll
    for (int kt = 0; kt < 128; kt += 32) {
        short8 a = *(const short8*)&As[(m_off + r16) * SL + kt + q * 8];
        short8 bb[8];
#pragma unroll
        for (int tn = 0; tn < 8; ++tn)
            bb[tn] = *(const short8*)&Bs[(tn * 16 + r16) * SL + kt + q * 8];
#pragma unroll
        for (int tn = 0; tn < 8; ++tn)
            acc[tn] = __builtin_amdgcn_mfma_f32_16x16x32_bf16(a, bb[tn], acc[tn], 0, 0, 0);
    }
#pragma unroll
    for (int r = 0; r < 4; ++r) {
        int row = m0 + m_off + q * 4 + r;
        if (row < N_NODES) {
#pragma unroll
            for (int tn = 0; tn < 8; ++tn)
                out[(size_t)row * 128 + tn * 16 + r16] = f2bf(acc[tn][r]);
        }
    }
}

// ---------------- D2: atomic count+fill (bucket CSR) ----------------------
// NO LDS: atomics need max waves/CU (round-1/3 lesson: 3 blocks/CU -> 66us).

__global__ __launch_bounds__(256) void fill_k(const int* __restrict__ ei,
                                              int* __restrict__ deg,
                                              int* __restrict__ col) {
    int e = blockIdx.x * 256 + threadIdx.x;
    if (e < N_EDGES) {
        int s = ei[e];
        int d = ei[N_EDGES + e];
        int r = atomicAdd(&deg[d], 1);
        if (r < CAP) col[((size_t)d << 6) + r] = s;   // guard = corruption insurance
    }
}

// ---------------- D3: agg1(+bias+ReLU) -> LDS -> gemm2 --------------------
// Round-2 gather loop (best measured): shfl-broadcast col + 1-deep prefetch.
// W2 transposed fp32->bf16 in-kernel (no W2t round trip).

__global__ __launch_bounds__(256) void agg_gemm2(const u16* __restrict__ hs,
                                                 const int* __restrict__ deg,
                                                 const int* __restrict__ col,
                                                 const float* __restrict__ bias,
                                                 const float* __restrict__ W2,
                                                 u16* __restrict__ out) {
    __shared__ u16 As[64 * SL];
    __shared__ u16 Bs[64 * SL];
    const int tid = threadIdx.x;
    const int m0 = blockIdx.x * 64;
    {   // stage Bs[n][k] = bf16(W2[k][n]); W2 fp32 [128][64] row-major.
        // thread: n0=(t&15)*4, kp=t>>4 in [0,16), 4 passes over k.
        int n0 = (tid & 15) * 4, kp = tid >> 4;
#pragma unroll
        for (int p = 0; p < 4; ++p) {
            int k = p * 32 + kp * 2;
            float4 r0 = *(const float4*)&W2[(k) * 64 + n0];
            float4 r1 = *(const float4*)&W2[(k + 1) * 64 + n0];
            *(u32*)&Bs[(n0 + 0) * SL + k] = (u32)f2bf(r0.x) | ((u32)f2bf(r1.x) << 16);
            *(u32*)&Bs[(n0 + 1) * SL + k] = (u32)f2bf(r0.y) | ((u32)f2bf(r1.y) << 16);
            *(u32*)&Bs[(n0 + 2) * SL + k] = (u32)f2bf(r0.z) | ((u32)f2bf(r1.z) << 16);
            *(u32*)&Bs[(n0 + 3) * SL + k] = (u32)f2bf(r0.w) | ((u32)f2bf(r1.w) << 16);
        }
    }
    const uint4* rows = (const uint4*)hs;  // 16 uint4 per 128-feat row
    const int lane = tid & 15;
    const int sub = lane & 7;
    const int fo = lane * 8;
#pragma unroll
    for (int p = 0; p < 4; ++p) {
        int nl = p * 16 + (tid >> 4);      // node_local in [0,64)
        int node = m0 + nl;
        uint4 pk = make_uint4(0, 0, 0, 0);
        if (node < N_NODES) {
            int dg = deg[node];
            float dv = rsqrtf((float)(dg + 1));
            float acc[8];
            uint4 sv = rows[(size_t)node * 16 + lane];  // self-loop
            acc[0] = dv * bf_lo(sv.x); acc[1] = dv * bf_hi(sv.x);
            acc[2] = dv * bf_lo(sv.y); acc[3] = dv * bf_hi(sv.y);
            acc[4] = dv * bf_lo(sv.z); acc[5] = dv * bf_hi(sv.z);
            acc[6] = dv * bf_lo(sv.w); acc[7] = dv * bf_hi(sv.w);
            const int* crow = col + ((size_t)node << 6);
            int c = crow[sub];
            c = (sub < dg) ? c : 0;
            float scr = rsqrtf((float)(deg[c] + 1));
            float sc = (sub < dg) ? scr : 0.f;
            for (int r0 = 0; r0 < dg; r0 += 8) {
                int jn = r0 + 8 + sub;   // prefetch next round
                int cn = crow[jn & (CAP - 1)];
                cn = (jn < dg) ? cn : 0;
                float scnr = rsqrtf((float)(deg[cn] + 1));
                float scn = (jn < dg) ? scnr : 0.f;
#pragma unroll
                for (int jj = 0; jj < 8; ++jj) {
                    int cj = __shfl(c, jj, 16);
                    float scj = __shfl(sc, jj, 16);   // 0 for padding slots
                    uint4 v = rows[(size_t)cj * 16 + lane];
                    acc[0] = fmaf(scj, bf_lo(v.x), acc[0]);
                    acc[1] = fmaf(scj, bf_hi(v.x), acc[1]);
                    acc[2] = fmaf(scj, bf_lo(v.y), acc[2]);
                    acc[3] = fmaf(scj, bf_hi(v.y), acc[3]);
                    acc[4] = fmaf(scj, bf_lo(v.z), acc[4]);
                    acc[5] = fmaf(scj, bf_hi(v.z), acc[5]);
                    acc[6] = fmaf(scj, bf_lo(v.w), acc[6]);
                    acc[7] = fmaf(scj, bf_hi(v.w), acc[7]);
                }
                c = cn; sc = scn;
            }
            u32 w0[4];
#pragma unroll
            for (int jq = 0; jq < 4; ++jq) {
                u16 a = f2bf(fmaxf(fmaf(dv, acc[2 * jq], bias[fo + 2 * jq]), 0.f));
                u16 bq = f2bf(fmaxf(fmaf(dv, acc[2 * jq + 1], bias[fo + 2 * jq + 1]), 0.f));
                w0[jq] = (u32)a | ((u32)bq << 16);
            }
            pk = make_uint4(w0[0], w0[1], w0[2], w0[3]);
        }
        *(uint4*)&As[nl * SL + fo] = pk;
    }
    __syncthreads();

    // gemm2 phase: M=64, N=64, K=128; output pre-scaled by dinv[row]
    const int l = tid & 63, w = tid >> 6;
    const int q = l >> 4, r16 = l & 15;
    const int m_off = w * 16;
    f32x4 acc2[4] = {};
#pragma unroll
    for (int kt = 0; kt < 128; kt += 32) {
        short8 a = *(const short8*)&As[(m_off + r16) * SL + kt + q * 8];
        short8 bb[4];
#pragma unroll
        for (int tn = 0; tn < 4; ++tn)
            bb[tn] = *(const short8*)&Bs[(tn * 16 + r16) * SL + kt + q * 8];
#pragma unroll
        for (int tn = 0; tn < 4; ++tn)
            acc2[tn] = __builtin_amdgcn_mfma_f32_16x16x32_bf16(a, bb[tn], acc2[tn], 0, 0, 0);
    }
#pragma unroll
    for (int r = 0; r < 4; ++r) {
        int row = m0 + m_off + q * 4 + r;
        if (row < N_NODES) {
            float dvr = rsqrtf((float)(deg[row] + 1));
#pragma unroll
            for (int tn = 0; tn < 4; ++tn)
                out[(size_t)row * 64 + tn * 16 + r16] = f2bf(acc2[tn][r] * dvr);
        }
    }
}

// ---------------- D4: layer-2 aggregation + head (round-2 version) --------

__global__ __launch_bounds__(256) void agg_final_bf(const u16* __restrict__ hs,
                                                    const int* __restrict__ deg,
                                                    const int* __restrict__ col,
                                                    const float* __restrict__ b2,
                                                    const float* __restrict__ W3,
                                                    const float* __restrict__ b3,
                                                    float* __restrict__ out) {
    int node = blockIdx.x * 32 + (threadIdx.x >> 3);
    int lane = threadIdx.x & 7;
    if (node >= N_NODES) return;
    const uint4* rows = (const uint4*)hs;  // 8 uint4 per 64-feat row
    int dg = deg[node];
    float acc[8] = {};
    auto accum = [&](uint4 v) {
        acc[0] += bf_lo(v.x); acc[1] += bf_hi(v.x);
        acc[2] += bf_lo(v.y); acc[3] += bf_hi(v.y);
        acc[4] += bf_lo(v.z); acc[5] += bf_hi(v.z);
        acc[6] += bf_lo(v.w); acc[7] += bf_hi(v.w);
    };
    accum(rows[(size_t)node * 8 + lane]);  // self-loop (carries dinv[node])
    const int* crow = col + ((size_t)node << 6);
    int c = crow[lane];
    c = (lane < dg) ? c : 0;
    for (int r0 = 0; r0 < dg; r0 += 8) {
        int jn = r0 + 8 + lane;
        int cn = crow[jn & (CAP - 1)];
        cn = (jn < dg) ? cn : 0;
#pragma unroll
        for (int jj = 0; jj < 8; ++jj) {
            int cj = __shfl(c, jj, 8);
            uint4 v = rows[(size_t)cj * 8 + lane];
            uint4 vv = (r0 + jj < dg) ? v : make_uint4(0, 0, 0, 0);
            accum(vv);
        }
        c = cn;
    }
    float dv = rsqrtf((float)(dg + 1));
    int fo = lane * 8;
    float vsum = 0.f;
#pragma unroll
    for (int jq = 0; jq < 8; ++jq)
        vsum += fmaxf(fmaf(dv, acc[jq], b2[fo + jq]), 0.f) * W3[fo + jq];
#pragma unroll
    for (int m = 4; m > 0; m >>= 1) vsum += __shfl_xor(vsum, m, 64);
    if (lane == 0) out[node] = vsum + b3[0];
}

// ---------------- launch ----------------

extern "C" void kernel_launch(void* const* d_in, const int* in_sizes, int n_in,
                              void* d_out, int out_size, void* d_ws, size_t ws_size,
                              hipStream_t stream) {
    const float* x  = (const float*)d_in[0];
    const int*   ei = (const int*)d_in[1];
    const float* W1 = (const float*)d_in[2];
    const float* b1 = (const float*)d_in[3];
    const float* W2 = (const float*)d_in[4];
    const float* b2 = (const float*)d_in[5];
    const float* W3 = (const float*)d_in[6];
    const float* b3 = (const float*)d_in[7];
    float* out = (float*)d_out;

    char* ws = (char*)d_ws;
    size_t off = 0;
    auto alloc = [&](size_t bytes) -> void* {
        void* p = ws + off;
        off = (off + bytes + 255) & ~(size_t)255;
        return p;
    };
    int* deg = (int*)alloc(N_NODES * sizeof(int));
    int* col = (int*)alloc(((size_t)N_NODES * CAP + 64) * sizeof(int));  // +pad
    u16* hs1 = (u16*)alloc((size_t)N_NODES * 128 * sizeof(u16));
    u16* hs2 = (u16*)alloc((size_t)N_NODES * 64 * sizeof(u16));

    gemm1z_k<<<GB1, 256, 0, stream>>>(x, W1, hs1, deg);
    fill_k<<<FB, 256, 0, stream>>>(ei, deg, col);
    agg_gemm2<<<GB1, 256, 0, stream>>>(hs1, deg, col, b1, W2, hs2);
    agg_final_bf<<<(N_NODES + 31) / 32, 256, 0, stream>>>(hs2, deg, col, b2, W3, b3, out);
}